// Round 2
// baseline (727.398 us; speedup 1.0000x reference)
//
#include <hip/hip_runtime.h>
#include <hip/hip_bf16.h>

// ---------- types ----------
typedef __attribute__((ext_vector_type(8))) short short8;   // 8 x bf16 (4 VGPR) MFMA frag
typedef __attribute__((ext_vector_type(4))) float f32x4;    // MFMA accumulator

#define SCALE 0.17677669529663687f   // 32^-0.5

__device__ __forceinline__ unsigned short f2bf(float f) {
    union { __hip_bfloat16 b; unsigned short u; } c;
    c.b = __float2bfloat16(f);
    return c.u;
}

__device__ __forceinline__ void gload_lds16(const unsigned short* g, unsigned short* l) {
    __builtin_amdgcn_global_load_lds((const __attribute__((address_space(1))) void*)g,
                                     (__attribute__((address_space(3))) void*)l, 16, 0, 0);
}

// ---------- 1) fused LayerNorm (x1 & x2), fp32 -> bf16 ----------
// one wave per row (512 elems, 8/lane), 4 rows per block
__global__ __launch_bounds__(256) void ln_kernel(
    const float* __restrict__ x1, const float* __restrict__ x2,
    const float* __restrict__ n1w, const float* __restrict__ n1b,
    const float* __restrict__ n2w, const float* __restrict__ n2b,
    unsigned short* __restrict__ xn1, unsigned short* __restrict__ xn2)
{
    int lane = threadIdx.x & 63;
    int row  = blockIdx.x * 4 + (threadIdx.x >> 6);      // 0..131071
    const float* src; const float* w; const float* b; unsigned short* dst;
    if (row < 65536) {
        src = x1 + (size_t)row * 512; w = n1w; b = n1b; dst = xn1 + (size_t)row * 512;
    } else {
        size_t r = (size_t)(row - 65536);
        src = x2 + r * 512; w = n2w; b = n2b; dst = xn2 + r * 512;
    }
    float4 v0 = *(const float4*)(src + lane * 4);
    float4 v1 = *(const float4*)(src + 256 + lane * 4);
    float s = v0.x + v0.y + v0.z + v0.w + v1.x + v1.y + v1.z + v1.w;
    float q = v0.x*v0.x + v0.y*v0.y + v0.z*v0.z + v0.w*v0.w
            + v1.x*v1.x + v1.y*v1.y + v1.z*v1.z + v1.w*v1.w;
#pragma unroll
    for (int m = 1; m < 64; m <<= 1) { s += __shfl_xor(s, m); q += __shfl_xor(q, m); }
    float mu  = s * (1.0f / 512.0f);
    float var = q * (1.0f / 512.0f) - mu * mu;
    float rs  = rsqrtf(var + 1e-5f);
    float4 w0 = *(const float4*)(w + lane * 4);
    float4 w1 = *(const float4*)(w + 256 + lane * 4);
    float4 b0 = *(const float4*)(b + lane * 4);
    float4 b1 = *(const float4*)(b + 256 + lane * 4);
    ushort4 o0, o1;
    o0.x = f2bf((v0.x - mu) * rs * w0.x + b0.x);
    o0.y = f2bf((v0.y - mu) * rs * w0.y + b0.y);
    o0.z = f2bf((v0.z - mu) * rs * w0.z + b0.z);
    o0.w = f2bf((v0.w - mu) * rs * w0.w + b0.w);
    o1.x = f2bf((v1.x - mu) * rs * w1.x + b1.x);
    o1.y = f2bf((v1.y - mu) * rs * w1.y + b1.y);
    o1.z = f2bf((v1.z - mu) * rs * w1.z + b1.z);
    o1.w = f2bf((v1.w - mu) * rs * w1.w + b1.w);
    *(ushort4*)(dst + lane * 4)       = o0;
    *(ushort4*)(dst + 256 + lane * 4) = o1;
}

// ---------- 2) weight transpose + fp32->bf16 ----------
// WqT[512][512]  = qkv2_w[k][n]        (q part, cols 0..512)
// WkvT[1024][512]= qkv1_w[k][512+n]    (k,v parts)
// WpT[512][512]  = proj_w[k][n]
__global__ __launch_bounds__(256) void wconv_kernel(
    const float* __restrict__ qkv1_w, const float* __restrict__ qkv2_w,
    const float* __restrict__ proj_w,
    unsigned short* __restrict__ WqT, unsigned short* __restrict__ WkvT,
    unsigned short* __restrict__ WpT)
{
    __shared__ float tile[32][33];
    int t = blockIdx.x;
    const float* src; int ldin, c0, tn, tk; unsigned short* dst;
    if (t < 256)      { src = qkv2_w; ldin = 1536; c0 = 0;   dst = WqT;  tn = t >> 4;        tk = t & 15; }
    else if (t < 768) { int u = t - 256; src = qkv1_w; ldin = 1536; c0 = 512; dst = WkvT; tn = u >> 4; tk = u & 15; }
    else              { int u = t - 768; src = proj_w; ldin = 512;  c0 = 0;   dst = WpT;  tn = u >> 4; tk = u & 15; }
    int lx = threadIdx.x & 31, ly = threadIdx.x >> 5;   // ly 0..7
#pragma unroll
    for (int i = 0; i < 4; i++)
        tile[ly + i * 8][lx] = src[(size_t)(tk * 32 + ly + i * 8) * ldin + c0 + tn * 32 + lx];
    __syncthreads();
#pragma unroll
    for (int i = 0; i < 4; i++)
        dst[(size_t)(tn * 32 + ly + i * 8) * 512 + tk * 32 + lx] = f2bf(tile[lx][ly + i * 8]);
}

// ---------- GEMM core: C(128x128) += A(128x512) * Wt(128x512)^T ----------
// A row-major lda=512 (bf16), Wt row-major (N x K) ldw=512 (bf16).
// 256 threads = 4 waves in 2x2; each wave 64x64 = 4x4 16x16x32 frags.
__device__ __forceinline__ void gemm_core(
    const unsigned short* __restrict__ A,
    const unsigned short* __restrict__ W,
    unsigned short* sA, unsigned short* sB,
    f32x4 acc[4][4])
{
    int tid = threadIdx.x, lane = tid & 63;
    int wv = tid >> 6, wr = wv >> 1, wc = wv & 1;
    int lr = lane & 15, lk = lane >> 4;
    for (int k0 = 0; k0 < 512; k0 += 64) {
#pragma unroll
        for (int i = 0; i < 4; i++) {
            int flat = i * 256 + tid;           // 0..1023 16B chunks
            int r = flat >> 3, cc = flat & 7;
            gload_lds16(A + (size_t)r * 512 + k0 + cc * 8, sA + flat * 8);
            gload_lds16(W + (size_t)r * 512 + k0 + cc * 8, sB + flat * 8);
        }
        __syncthreads();
#pragma unroll
        for (int ks = 0; ks < 2; ks++) {
            short8 a[4], b[4];
#pragma unroll
            for (int mi = 0; mi < 4; mi++)
                a[mi] = *(const short8*)(sA + (64 * wr + 16 * mi + lr) * 64 + ks * 32 + lk * 8);
#pragma unroll
            for (int ni = 0; ni < 4; ni++)
                b[ni] = *(const short8*)(sB + (64 * wc + 16 * ni + lr) * 64 + ks * 32 + lk * 8);
#pragma unroll
            for (int mi = 0; mi < 4; mi++)
#pragma unroll
                for (int ni = 0; ni < 4; ni++)
                    acc[mi][ni] = __builtin_amdgcn_mfma_f32_16x16x32_bf16(a[mi], b[ni], acc[mi][ni], 0, 0, 0);
        }
        __syncthreads();
    }
}

// ---------- 3) QKV GEMM: grid (512, 12). nb<4 -> Q from XN2, else KV from XN1 ----------
__global__ __launch_bounds__(256) void qkv_gemm_kernel(
    const unsigned short* __restrict__ XN1, const unsigned short* __restrict__ XN2,
    const unsigned short* __restrict__ WqT, const unsigned short* __restrict__ WkvT,
    const float* __restrict__ qkv1_b, const float* __restrict__ qkv2_b,
    unsigned short* __restrict__ Qb, unsigned short* __restrict__ KVb)
{
    __shared__ unsigned short sA[128 * 64];
    __shared__ unsigned short sB[128 * 64];
    int mb = blockIdx.x, nb = blockIdx.y;
    f32x4 acc[4][4];
#pragma unroll
    for (int mi = 0; mi < 4; mi++)
#pragma unroll
        for (int ni = 0; ni < 4; ni++) { f32x4 z = {0.f, 0.f, 0.f, 0.f}; acc[mi][ni] = z; }
    const unsigned short* Ap; const unsigned short* Wp;
    if (nb < 4) { Ap = XN2 + (size_t)mb * 128 * 512; Wp = WqT  + (size_t)nb * 128 * 512; }
    else        { Ap = XN1 + (size_t)mb * 128 * 512; Wp = WkvT + (size_t)(nb - 4) * 128 * 512; }
    gemm_core(Ap, Wp, sA, sB, acc);
    int lane = threadIdx.x & 63, wv = threadIdx.x >> 6;
    int wr = wv >> 1, wc = wv & 1, lr = lane & 15, lk = lane >> 4;
    if (nb < 4) {
#pragma unroll
        for (int ni = 0; ni < 4; ni++) {
            int col = nb * 128 + 64 * wc + 16 * ni + lr;
            float bias = qkv2_b[col];
#pragma unroll
            for (int mi = 0; mi < 4; mi++)
#pragma unroll
                for (int i = 0; i < 4; i++) {
                    int row = mb * 128 + 64 * wr + 16 * mi + 4 * lk + i;
                    Qb[(size_t)row * 512 + col] = f2bf((acc[mi][ni][i] + bias) * SCALE);
                }
        }
    } else {
#pragma unroll
        for (int ni = 0; ni < 4; ni++) {
            int col = (nb - 4) * 128 + 64 * wc + 16 * ni + lr;   // 0..1023: K then V
            float bias = qkv1_b[512 + col];
#pragma unroll
            for (int mi = 0; mi < 4; mi++)
#pragma unroll
                for (int i = 0; i < 4; i++) {
                    int row = mb * 128 + 64 * wr + 16 * mi + 4 * lk + i;
                    KVb[(size_t)row * 1024 + col] = f2bf(acc[mi][ni][i] + bias);
                }
        }
    }
}

// ---------- 4) windowed cross-attention: one wave per (window, head) ----------
__global__ __launch_bounds__(256) void attn_kernel(
    const unsigned short* __restrict__ Qb, const unsigned short* __restrict__ KVb,
    const float* __restrict__ rpb, unsigned short* __restrict__ AO)
{
    __shared__ unsigned short sV[4][64 * 32];
    __shared__ unsigned short sP[4][64 * 64];
    int wv = threadIdx.x >> 6, lane = threadIdx.x & 63;
    int lr = lane & 15, lk = lane >> 4;
    int u = blockIdx.x * 4 + wv;           // 0..16383
    int win = u >> 4, h = u & 15;
    int b = win >> 6, wi = win & 63;
    int rowbase = b * 4096 + (wi >> 3) * 512 + (wi & 7) * 8;
    unsigned short* myV = sV[wv];
    unsigned short* myP = sP[wv];

    // stage V rows into LDS (64 x 32 bf16)
#pragma unroll
    for (int i = 0; i < 4; i++) {
        int c = i * 64 + lane;             // 16B chunk id, 0..255
        int t = c >> 2, cc = c & 3;
        int grow = rowbase + (t >> 3) * 64 + (t & 7);
        *(short8*)(myV + t * 32 + cc * 8) =
            *(const short8*)(KVb + (size_t)grow * 1024 + 512 + h * 32 + cc * 8);
    }
    // Q & K fragments straight from global (16B contiguous per lane)
    short8 qf[4], kf[4];
#pragma unroll
    for (int fr = 0; fr < 4; fr++) {
        int t = 16 * fr + lr;
        int grow = rowbase + (t >> 3) * 64 + (t & 7);
        qf[fr] = *(const short8*)(Qb  + (size_t)grow * 512  + h * 32 + lk * 8);
        kf[fr] = *(const short8*)(KVb + (size_t)grow * 1024 + h * 32 + lk * 8);
    }
    // S = Q K^T  (64x64), one MFMA per 16x16 frag (K=32 = full head dim)
    f32x4 s[4][4];
#pragma unroll
    for (int fr = 0; fr < 4; fr++)
#pragma unroll
        for (int fc = 0; fc < 4; fc++) { f32x4 z = {0.f, 0.f, 0.f, 0.f}; s[fr][fc] = z; }
#pragma unroll
    for (int fr = 0; fr < 4; fr++)
#pragma unroll
        for (int fc = 0; fc < 4; fc++)
            s[fr][fc] = __builtin_amdgcn_mfma_f32_16x16x32_bf16(qf[fr], kf[fc], s[fr][fc], 0, 0, 0);

    // bias + wave-parallel softmax over m; store unnormalized exp to LDS (bf16, XOR-swizzled 16B chunks)
    float rinv[4][4];
#pragma unroll
    for (int fr = 0; fr < 4; fr++) {
#pragma unroll
        for (int i = 0; i < 4; i++) {
            int n = 16 * fr + 4 * lk + i;
#pragma unroll
            for (int fc = 0; fc < 4; fc++) {
                int m = 16 * fc + lr;
                int idx = ((n >> 3) - (m >> 3) + 7) * 15 + (n & 7) - (m & 7) + 7;
                s[fr][fc][i] += rpb[idx * 16 + h];
            }
            float v = fmaxf(fmaxf(s[fr][0][i], s[fr][1][i]), fmaxf(s[fr][2][i], s[fr][3][i]));
            v = fmaxf(v, __shfl_xor(v, 1)); v = fmaxf(v, __shfl_xor(v, 2));
            v = fmaxf(v, __shfl_xor(v, 4)); v = fmaxf(v, __shfl_xor(v, 8));
            float sum = 0.f;
#pragma unroll
            for (int fc = 0; fc < 4; fc++) {
                float e = __expf(s[fr][fc][i] - v);
                s[fr][fc][i] = e; sum += e;
            }
            sum += __shfl_xor(sum, 1); sum += __shfl_xor(sum, 2);
            sum += __shfl_xor(sum, 4); sum += __shfl_xor(sum, 8);
            rinv[fr][i] = 1.0f / sum;
#pragma unroll
            for (int fc = 0; fc < 4; fc++) {
                int m = 16 * fc + lr;
                int chunk = (m >> 3) ^ (n & 7);
                myP[n * 64 + chunk * 8 + (m & 7)] = f2bf(s[fr][fc][i]);
            }
        }
    }
    __syncthreads();

    // O = P V  (64x32): A-frags from swizzled LDS P, B-frags from LDS V columns
    f32x4 o[4][2];
#pragma unroll
    for (int fr = 0; fr < 4; fr++)
#pragma unroll
        for (int nj = 0; nj < 2; nj++) { f32x4 z = {0.f, 0.f, 0.f, 0.f}; o[fr][nj] = z; }
#pragma unroll
    for (int mk = 0; mk < 2; mk++) {
        short8 pa[4];
#pragma unroll
        for (int fr = 0; fr < 4; fr++) {
            int n = 16 * fr + lr;
            int chunk = (4 * mk + lk) ^ (n & 7);
            pa[fr] = *(const short8*)(myP + n * 64 + chunk * 8);
        }
#pragma unroll
        for (int nj = 0; nj < 2; nj++) {
            short8 vb;
#pragma unroll
            for (int j = 0; j < 8; j++)
                vb[j] = (short)myV[(32 * mk + 8 * lk + j) * 32 + 16 * nj + lr];
#pragma unroll
            for (int fr = 0; fr < 4; fr++)
                o[fr][nj] = __builtin_amdgcn_mfma_f32_16x16x32_bf16(pa[fr], vb, o[fr][nj], 0, 0, 0);
        }
    }
    // normalize rows and write out (feature col = h*32 + d)
#pragma unroll
    for (int fr = 0; fr < 4; fr++)
#pragma unroll
        for (int nj = 0; nj < 2; nj++)
#pragma unroll
            for (int i = 0; i < 4; i++) {
                int t = 16 * fr + 4 * lk + i;
                int grow = rowbase + (t >> 3) * 64 + (t & 7);
                AO[(size_t)grow * 512 + h * 32 + 16 * nj + lr] = f2bf(o[fr][nj][i] * rinv[fr][i]);
            }
}

// ---------- 5) proj GEMM + bias + residual (fp32 out) ----------
__global__ __launch_bounds__(256) void proj_gemm_kernel(
    const unsigned short* __restrict__ AO, const unsigned short* __restrict__ WpT,
    const float* __restrict__ proj_b, const float* __restrict__ x1,
    float* __restrict__ out)
{
    __shared__ unsigned short sA[128 * 64];
    __shared__ unsigned short sB[128 * 64];
    int mb = blockIdx.x, nb = blockIdx.y;
    f32x4 acc[4][4];
#pragma unroll
    for (int mi = 0; mi < 4; mi++)
#pragma unroll
        for (int ni = 0; ni < 4; ni++) { f32x4 z = {0.f, 0.f, 0.f, 0.f}; acc[mi][ni] = z; }
    gemm_core(AO + (size_t)mb * 128 * 512, WpT + (size_t)nb * 128 * 512, sA, sB, acc);
    int lane = threadIdx.x & 63, wv = threadIdx.x >> 6;
    int wr = wv >> 1, wc = wv & 1, lr = lane & 15, lk = lane >> 4;
#pragma unroll
    for (int ni = 0; ni < 4; ni++) {
        int col = nb * 128 + 64 * wc + 16 * ni + lr;
        float bias = proj_b[col];
#pragma unroll
        for (int mi = 0; mi < 4; mi++)
#pragma unroll
            for (int i = 0; i < 4; i++) {
                int row = mb * 128 + 64 * wr + 16 * mi + 4 * lk + i;
                out[(size_t)row * 512 + col] = acc[mi][ni][i] + bias + x1[(size_t)row * 512 + col];
            }
    }
}

// ---------- launch ----------
extern "C" void kernel_launch(void* const* d_in, const int* in_sizes, int n_in,
                              void* d_out, int out_size, void* d_ws, size_t ws_size,
                              hipStream_t stream)
{
    const float* x1     = (const float*)d_in[0];
    const float* x2     = (const float*)d_in[1];
    const float* n1w    = (const float*)d_in[2];
    const float* n1b    = (const float*)d_in[3];
    const float* n2w    = (const float*)d_in[4];
    const float* n2b    = (const float*)d_in[5];
    const float* qkv1_w = (const float*)d_in[6];
    const float* qkv1_b = (const float*)d_in[7];
    const float* qkv2_w = (const float*)d_in[8];
    const float* qkv2_b = (const float*)d_in[9];
    const float* rpb    = (const float*)d_in[10];
    const float* proj_w = (const float*)d_in[11];
    const float* proj_b = (const float*)d_in[12];
    float* out = (float*)d_out;

    char* ws = (char*)d_ws;
    const size_t SZ = 67108864;   // 65536*512*2 bytes
    unsigned short* XN1  = (unsigned short*)(ws);
    unsigned short* XN2  = (unsigned short*)(ws + SZ);
    unsigned short* Qb   = (unsigned short*)(ws + 2 * SZ);
    unsigned short* KVb  = (unsigned short*)(ws + 3 * SZ);       // 128MB (K then V)
    unsigned short* WqT  = (unsigned short*)(ws + 5 * SZ);
    unsigned short* WkvT = WqT + 512 * 512;
    unsigned short* WpT  = WkvT + 1024 * 512;
    unsigned short* AO   = XN2;   // XN2 is dead after qkv_gemm; reuse for attention output

    hipLaunchKernelGGL(ln_kernel,        dim3(32768),   dim3(256), 0, stream,
                       x1, x2, n1w, n1b, n2w, n2b, XN1, XN2);
    hipLaunchKernelGGL(wconv_kernel,     dim3(1024),    dim3(256), 0, stream,
                       qkv1_w, qkv2_w, proj_w, WqT, WkvT, WpT);
    hipLaunchKernelGGL(qkv_gemm_kernel,  dim3(512, 12), dim3(256), 0, stream,
                       XN1, XN2, WqT, WkvT, qkv1_b, qkv2_b, Qb, KVb);
    hipLaunchKernelGGL(attn_kernel,      dim3(4096),    dim3(256), 0, stream,
                       Qb, KVb, rpb, AO);
    hipLaunchKernelGGL(proj_gemm_kernel, dim3(512, 4),  dim3(256), 0, stream,
                       AO, WpT, proj_b, x1, out);
}

// Round 6
// 675.933 us; speedup vs baseline: 1.0761x; 1.0761x over previous
//
#include <hip/hip_runtime.h>
#include <hip/hip_bf16.h>

// ---------- types ----------
typedef __attribute__((ext_vector_type(8))) short short8;   // 8 x bf16 (4 VGPR) MFMA frag
typedef __attribute__((ext_vector_type(4))) float f32x4;    // MFMA accumulator

#define SCALE 0.17677669529663687f   // 32^-0.5

__device__ __forceinline__ unsigned short f2bf(float f) {
    union { __hip_bfloat16 b; unsigned short u; } c;
    c.b = __float2bfloat16(f);
    return c.u;
}

__device__ __forceinline__ void gload_lds16(const unsigned short* g, unsigned short* l) {
    __builtin_amdgcn_global_load_lds((const __attribute__((address_space(1))) void*)g,
                                     (__attribute__((address_space(3))) void*)l, 16, 0, 0);
}

// ---------- 1) fused LayerNorm (x1 & x2), fp32 -> bf16 ----------
__global__ __launch_bounds__(256) void ln_kernel(
    const float* __restrict__ x1, const float* __restrict__ x2,
    const float* __restrict__ n1w, const float* __restrict__ n1b,
    const float* __restrict__ n2w, const float* __restrict__ n2b,
    unsigned short* __restrict__ xn1, unsigned short* __restrict__ xn2)
{
    int lane = threadIdx.x & 63;
    int row  = blockIdx.x * 4 + (threadIdx.x >> 6);      // 0..131071
    const float* src; const float* w; const float* b; unsigned short* dst;
    if (row < 65536) {
        src = x1 + (size_t)row * 512; w = n1w; b = n1b; dst = xn1 + (size_t)row * 512;
    } else {
        size_t r = (size_t)(row - 65536);
        src = x2 + r * 512; w = n2w; b = n2b; dst = xn2 + r * 512;
    }
    float4 v0 = *(const float4*)(src + lane * 4);
    float4 v1 = *(const float4*)(src + 256 + lane * 4);
    float s = v0.x + v0.y + v0.z + v0.w + v1.x + v1.y + v1.z + v1.w;
    float q = v0.x*v0.x + v0.y*v0.y + v0.z*v0.z + v0.w*v0.w
            + v1.x*v1.x + v1.y*v1.y + v1.z*v1.z + v1.w*v1.w;
#pragma unroll
    for (int m = 1; m < 64; m <<= 1) { s += __shfl_xor(s, m); q += __shfl_xor(q, m); }
    float mu  = s * (1.0f / 512.0f);
    float var = q * (1.0f / 512.0f) - mu * mu;
    float rs  = rsqrtf(var + 1e-5f);
    float4 w0 = *(const float4*)(w + lane * 4);
    float4 w1 = *(const float4*)(w + 256 + lane * 4);
    float4 b0 = *(const float4*)(b + lane * 4);
    float4 b1 = *(const float4*)(b + 256 + lane * 4);
    ushort4 o0, o1;
    o0.x = f2bf((v0.x - mu) * rs * w0.x + b0.x);
    o0.y = f2bf((v0.y - mu) * rs * w0.y + b0.y);
    o0.z = f2bf((v0.z - mu) * rs * w0.z + b0.z);
    o0.w = f2bf((v0.w - mu) * rs * w0.w + b0.w);
    o1.x = f2bf((v1.x - mu) * rs * w1.x + b1.x);
    o1.y = f2bf((v1.y - mu) * rs * w1.y + b1.y);
    o1.z = f2bf((v1.z - mu) * rs * w1.z + b1.z);
    o1.w = f2bf((v1.w - mu) * rs * w1.w + b1.w);
    *(ushort4*)(dst + lane * 4)       = o0;
    *(ushort4*)(dst + 256 + lane * 4) = o1;
}

// ---------- 2) weight transpose + fp32->bf16 ----------
__global__ __launch_bounds__(256) void wconv_kernel(
    const float* __restrict__ qkv1_w, const float* __restrict__ qkv2_w,
    const float* __restrict__ proj_w,
    unsigned short* __restrict__ WqT, unsigned short* __restrict__ WkvT,
    unsigned short* __restrict__ WpT)
{
    __shared__ float tile[32][33];
    int t = blockIdx.x;
    const float* src; int ldin, c0, tn, tk; unsigned short* dst;
    if (t < 256)      { src = qkv2_w; ldin = 1536; c0 = 0;   dst = WqT;  tn = t >> 4;        tk = t & 15; }
    else if (t < 768) { int u = t - 256; src = qkv1_w; ldin = 1536; c0 = 512; dst = WkvT; tn = u >> 4; tk = u & 15; }
    else              { int u = t - 768; src = proj_w; ldin = 512;  c0 = 0;   dst = WpT;  tn = u >> 4; tk = u & 15; }
    int lx = threadIdx.x & 31, ly = threadIdx.x >> 5;   // ly 0..7
#pragma unroll
    for (int i = 0; i < 4; i++)
        tile[ly + i * 8][lx] = src[(size_t)(tk * 32 + ly + i * 8) * ldin + c0 + tn * 32 + lx];
    __syncthreads();
#pragma unroll
    for (int i = 0; i < 4; i++)
        dst[(size_t)(tn * 32 + ly + i * 8) * 512 + tk * 32 + lx] = f2bf(tile[lx][ly + i * 8]);
}

// =================== 256x256 phased GEMM core (T2+T3+T4+T5) ===================
// A row-major [M][512] bf16; W row-major [N][512] bf16 (B^T form). K=512 fixed.
// 512 threads = 8 waves (2M x 4N); per-wave output 128x64 = 8x4 16x16x32 frags.
// LDS 128KB: 2 K-tile dbuf x (A 256x64 + B 256x64), subtiled [16r][32k] with
// chunk-XOR swizzle q ^= (r>>1)&3 (conflict-free ds_read_b128).
// Per K-tile: 2 phases (k-half each): 12 ds_read + 1 stage-unit (4 gload_lds)
// + 32 MFMA; vmcnt(8) per phase (counted, never 0 mid-loop).

__device__ __forceinline__ void stage_unit(
    unsigned short* lds, const unsigned short* A, const unsigned short* W,
    int tile, int s, int wv, int sr, int sq, int dst_lane)
{
    int buf = (tile & 1) << 15;           // 32768 elements per K-tile buffer
    int k0  = tile * 64 + s * 32;
#pragma unroll
    for (int i = 0; i < 2; i++) {
        int R   = i * 8 + wv;             // subtile row 0..15
        int sub = (R * 2 + s) << 9;       // subtile offset (elements)
        gload_lds16(A + (size_t)(R * 16 + sr) * 512 + k0 + sq * 8,
                    lds + buf + sub + dst_lane);
        gload_lds16(W + (size_t)(R * 16 + sr) * 512 + k0 + sq * 8,
                    lds + buf + 16384 + sub + dst_lane);
    }
}

template<int VM, bool DOST>
__device__ __forceinline__ void gphase(
    unsigned short* lds, const unsigned short* A, const unsigned short* W,
    f32x4 (&acc)[8][4], int tile, int s, int st_t, int st_s,
    int wr, int wc, int wv, int rdoff, int sr, int sq, int dst_lane)
{
    if constexpr (VM == 8)      asm volatile("s_waitcnt vmcnt(8)" ::: "memory");
    else if constexpr (VM == 4) asm volatile("s_waitcnt vmcnt(4)" ::: "memory");
    else                        asm volatile("s_waitcnt vmcnt(0)" ::: "memory");
    __builtin_amdgcn_s_barrier();
    __builtin_amdgcn_sched_barrier(0);
    int buf = (tile & 1) << 15;
    short8 a[8], b[4];
#pragma unroll
    for (int mi = 0; mi < 8; mi++)
        a[mi] = *(const short8*)(lds + buf + (((wr * 8 + mi) * 2 + s) << 9) + rdoff);
#pragma unroll
    for (int ni = 0; ni < 4; ni++)
        b[ni] = *(const short8*)(lds + buf + 16384 + (((wc * 4 + ni) * 2 + s) << 9) + rdoff);
    if constexpr (DOST) stage_unit(lds, A, W, st_t, st_s, wv, sr, sq, dst_lane);
    __builtin_amdgcn_s_setprio(1);
#pragma unroll
    for (int mi = 0; mi < 8; mi++)
#pragma unroll
        for (int ni = 0; ni < 4; ni++)
            acc[mi][ni] = __builtin_amdgcn_mfma_f32_16x16x32_bf16(a[mi], b[ni], acc[mi][ni], 0, 0, 0);
    __builtin_amdgcn_s_setprio(0);
}

__device__ __forceinline__ void gemm256(
    unsigned short* lds, const unsigned short* A, const unsigned short* W,
    f32x4 (&acc)[8][4])
{
    int tid = threadIdx.x, lane = tid & 63, wv = tid >> 6;
    int wr = wv >> 2, wc = wv & 3;
    int lr = lane & 15, lk = lane >> 4;
    int rdoff    = lr * 32 + ((lk ^ ((lr >> 1) & 3)) << 3);  // swizzled frag addr
    int sr       = lane >> 2;                                 // stage row in subtile
    int sq       = (lane & 3) ^ ((sr >> 1) & 3);              // inverse-swz src chunk
    int dst_lane = lane * 8;                                  // linear LDS dest

    // prologue: fully stage K-tiles 0 and 1 (16 loads in flight)
    stage_unit(lds, A, W, 0, 0, wv, sr, sq, dst_lane);
    stage_unit(lds, A, W, 0, 1, wv, sr, sq, dst_lane);
    stage_unit(lds, A, W, 1, 0, wv, sr, sq, dst_lane);
    stage_unit(lds, A, W, 1, 1, wv, sr, sq, dst_lane);

    gphase<8,false>(lds, A, W, acc, 0, 0, 0, 0, wr, wc, wv, rdoff, sr, sq, dst_lane);
    gphase<8,true >(lds, A, W, acc, 0, 1, 2, 0, wr, wc, wv, rdoff, sr, sq, dst_lane);
    gphase<8,true >(lds, A, W, acc, 1, 0, 2, 1, wr, wc, wv, rdoff, sr, sq, dst_lane);
    gphase<8,true >(lds, A, W, acc, 1, 1, 3, 0, wr, wc, wv, rdoff, sr, sq, dst_lane);
    gphase<8,true >(lds, A, W, acc, 2, 0, 3, 1, wr, wc, wv, rdoff, sr, sq, dst_lane);
    gphase<8,true >(lds, A, W, acc, 2, 1, 4, 0, wr, wc, wv, rdoff, sr, sq, dst_lane);
    gphase<8,true >(lds, A, W, acc, 3, 0, 4, 1, wr, wc, wv, rdoff, sr, sq, dst_lane);
    gphase<8,true >(lds, A, W, acc, 3, 1, 5, 0, wr, wc, wv, rdoff, sr, sq, dst_lane);
    gphase<8,true >(lds, A, W, acc, 4, 0, 5, 1, wr, wc, wv, rdoff, sr, sq, dst_lane);
    gphase<8,true >(lds, A, W, acc, 4, 1, 6, 0, wr, wc, wv, rdoff, sr, sq, dst_lane);
    gphase<8,true >(lds, A, W, acc, 5, 0, 6, 1, wr, wc, wv, rdoff, sr, sq, dst_lane);
    gphase<8,true >(lds, A, W, acc, 5, 1, 7, 0, wr, wc, wv, rdoff, sr, sq, dst_lane);
    gphase<8,true >(lds, A, W, acc, 6, 0, 7, 1, wr, wc, wv, rdoff, sr, sq, dst_lane);
    gphase<8,false>(lds, A, W, acc, 6, 1, 0, 0, wr, wc, wv, rdoff, sr, sq, dst_lane);
    gphase<4,false>(lds, A, W, acc, 7, 0, 0, 0, wr, wc, wv, rdoff, sr, sq, dst_lane);
    gphase<0,false>(lds, A, W, acc, 7, 1, 0, 0, wr, wc, wv, rdoff, sr, sq, dst_lane);
}

// ---------- 3) QKV GEMM: 1536 blocks (256 mb x 6 nb). nb<2 -> Q, else KV ----------
__global__ __launch_bounds__(512) void qkv_gemm256(
    const unsigned short* __restrict__ XN1, const unsigned short* __restrict__ XN2,
    const unsigned short* __restrict__ WqT, const unsigned short* __restrict__ WkvT,
    const float* __restrict__ qkv1_b, const float* __restrict__ qkv2_b,
    unsigned short* __restrict__ Qb, unsigned short* __restrict__ KVb)
{
    __shared__ unsigned short lds[65536];   // 128 KiB
    int bid = blockIdx.x;
    int wg  = (bid & 7) * 192 + (bid >> 3);    // XCD-bijective (1536 = 8*192)
    int mb  = wg / 6, nb = wg % 6;             // 6 n-tiles of one m-tile per XCD chunk
    f32x4 acc[8][4];
#pragma unroll
    for (int mi = 0; mi < 8; mi++)
#pragma unroll
        for (int ni = 0; ni < 4; ni++) { f32x4 z = {0.f,0.f,0.f,0.f}; acc[mi][ni] = z; }
    const unsigned short* A; const unsigned short* W;
    if (nb < 2) { A = XN2 + (size_t)mb * 256 * 512; W = WqT  + (size_t)nb * 256 * 512; }
    else        { A = XN1 + (size_t)mb * 256 * 512; W = WkvT + (size_t)(nb - 2) * 256 * 512; }
    gemm256(lds, A, W, acc);

    int lane = threadIdx.x & 63, wv = threadIdx.x >> 6;
    int wr = wv >> 2, wc = wv & 3, lr = lane & 15, lk = lane >> 4;
    int base_m = mb * 256 + wr * 128;
    if (nb < 2) {
#pragma unroll
        for (int ni = 0; ni < 4; ni++) {
            int col = nb * 256 + wc * 64 + ni * 16 + lr;
            float bias = qkv2_b[col];
#pragma unroll
            for (int mi = 0; mi < 8; mi++)
#pragma unroll
                for (int ii = 0; ii < 4; ii++) {
                    int row = base_m + mi * 16 + lk * 4 + ii;
                    Qb[(size_t)row * 512 + col] = f2bf((acc[mi][ni][ii] + bias) * SCALE);
                }
        }
    } else {
#pragma unroll
        for (int ni = 0; ni < 4; ni++) {
            int col = (nb - 2) * 256 + wc * 64 + ni * 16 + lr;   // 0..1023: K then V
            float bias = qkv1_b[512 + col];
#pragma unroll
            for (int mi = 0; mi < 8; mi++)
#pragma unroll
                for (int ii = 0; ii < 4; ii++) {
                    int row = base_m + mi * 16 + lk * 4 + ii;
                    KVb[(size_t)row * 1024 + col] = f2bf(acc[mi][ni][ii] + bias);
                }
        }
    }
}

// ---------- 5) proj GEMM + bias + residual: 512 blocks (256 mb x 2 nb) ----------
__global__ __launch_bounds__(512) void proj_gemm256(
    const unsigned short* __restrict__ AO, const unsigned short* __restrict__ WpT,
    const float* __restrict__ proj_b, const float* __restrict__ x1,
    float* __restrict__ out)
{
    __shared__ unsigned short lds[65536];
    int bid = blockIdx.x;
    int wg  = (bid & 7) * 64 + (bid >> 3);     // XCD-bijective (512 = 8*64)
    int mb  = wg >> 1, nb = wg & 1;
    f32x4 acc[8][4];
#pragma unroll
    for (int mi = 0; mi < 8; mi++)
#pragma unroll
        for (int ni = 0; ni < 4; ni++) { f32x4 z = {0.f,0.f,0.f,0.f}; acc[mi][ni] = z; }
    gemm256(lds, AO + (size_t)mb * 256 * 512, WpT + (size_t)nb * 256 * 512, acc);

    int lane = threadIdx.x & 63, wv = threadIdx.x >> 6;
    int wr = wv >> 2, wc = wv & 3, lr = lane & 15, lk = lane >> 4;
    int base_m = mb * 256 + wr * 128;
#pragma unroll
    for (int ni = 0; ni < 4; ni++) {
        int col = nb * 256 + wc * 64 + ni * 16 + lr;
        float bias = proj_b[col];
#pragma unroll
        for (int mi = 0; mi < 8; mi++)
#pragma unroll
            for (int ii = 0; ii < 4; ii++) {
                int row = base_m + mi * 16 + lk * 4 + ii;
                out[(size_t)row * 512 + col] = acc[mi][ni][ii] + bias + x1[(size_t)row * 512 + col];
            }
    }
}

// ---------- 4) windowed cross-attention: one wave per (window, head) ----------
__global__ __launch_bounds__(256) void attn_kernel(
    const unsigned short* __restrict__ Qb, const unsigned short* __restrict__ KVb,
    const float* __restrict__ rpb, unsigned short* __restrict__ AO)
{
    __shared__ unsigned short sV[4][64 * 32];
    __shared__ unsigned short sP[4][64 * 64];
    int wv = threadIdx.x >> 6, lane = threadIdx.x & 63;
    int lr = lane & 15, lk = lane >> 4;
    int u = blockIdx.x * 4 + wv;           // 0..16383
    int win = u >> 4, h = u & 15;
    int b = win >> 6, wi = win & 63;
    int rowbase = b * 4096 + (wi >> 3) * 512 + (wi & 7) * 8;
    unsigned short* myV = sV[wv];
    unsigned short* myP = sP[wv];

#pragma unroll
    for (int i = 0; i < 4; i++) {
        int c = i * 64 + lane;             // 16B chunk id, 0..255
        int t = c >> 2, cc = c & 3;
        int grow = rowbase + (t >> 3) * 64 + (t & 7);
        *(short8*)(myV + t * 32 + cc * 8) =
            *(const short8*)(KVb + (size_t)grow * 1024 + 512 + h * 32 + cc * 8);
    }
    short8 qf[4], kf[4];
#pragma unroll
    for (int fr = 0; fr < 4; fr++) {
        int t = 16 * fr + lr;
        int grow = rowbase + (t >> 3) * 64 + (t & 7);
        qf[fr] = *(const short8*)(Qb  + (size_t)grow * 512  + h * 32 + lk * 8);
        kf[fr] = *(const short8*)(KVb + (size_t)grow * 1024 + h * 32 + lk * 8);
    }
    f32x4 s[4][4];
#pragma unroll
    for (int fr = 0; fr < 4; fr++)
#pragma unroll
        for (int fc = 0; fc < 4; fc++) { f32x4 z = {0.f,0.f,0.f,0.f}; s[fr][fc] = z; }
#pragma unroll
    for (int fr = 0; fr < 4; fr++)
#pragma unroll
        for (int fc = 0; fc < 4; fc++)
            s[fr][fc] = __builtin_amdgcn_mfma_f32_16x16x32_bf16(qf[fr], kf[fc], s[fr][fc], 0, 0, 0);

    float rinv[4][4];
#pragma unroll
    for (int fr = 0; fr < 4; fr++) {
#pragma unroll
        for (int i = 0; i < 4; i++) {
            int n = 16 * fr + 4 * lk + i;
#pragma unroll
            for (int fc = 0; fc < 4; fc++) {
                int m = 16 * fc + lr;
                int idx = ((n >> 3) - (m >> 3) + 7) * 15 + (n & 7) - (m & 7) + 7;
                s[fr][fc][i] += rpb[idx * 16 + h];
            }
            float v = fmaxf(fmaxf(s[fr][0][i], s[fr][1][i]), fmaxf(s[fr][2][i], s[fr][3][i]));
            v = fmaxf(v, __shfl_xor(v, 1)); v = fmaxf(v, __shfl_xor(v, 2));
            v = fmaxf(v, __shfl_xor(v, 4)); v = fmaxf(v, __shfl_xor(v, 8));
            float sum = 0.f;
#pragma unroll
            for (int fc = 0; fc < 4; fc++) {
                float e = __expf(s[fr][fc][i] - v);
                s[fr][fc][i] = e; sum += e;
            }
            sum += __shfl_xor(sum, 1); sum += __shfl_xor(sum, 2);
            sum += __shfl_xor(sum, 4); sum += __shfl_xor(sum, 8);
            rinv[fr][i] = 1.0f / sum;
#pragma unroll
            for (int fc = 0; fc < 4; fc++) {
                int m = 16 * fc + lr;
                int chunk = (m >> 3) ^ (n & 7);
                myP[n * 64 + chunk * 8 + (m & 7)] = f2bf(s[fr][fc][i]);
            }
        }
    }
    __syncthreads();

    f32x4 o[4][2];
#pragma unroll
    for (int fr = 0; fr < 4; fr++)
#pragma unroll
        for (int nj = 0; nj < 2; nj++) { f32x4 z = {0.f,0.f,0.f,0.f}; o[fr][nj] = z; }
#pragma unroll
    for (int mk = 0; mk < 2; mk++) {
        short8 pa[4];
#pragma unroll
        for (int fr = 0; fr < 4; fr++) {
            int n = 16 * fr + lr;
            int chunk = (4 * mk + lk) ^ (n & 7);
            pa[fr] = *(const short8*)(myP + n * 64 + chunk * 8);
        }
#pragma unroll
        for (int nj = 0; nj < 2; nj++) {
            short8 vb;
#pragma unroll
            for (int j = 0; j < 8; j++)
                vb[j] = (short)myV[(32 * mk + 8 * lk + j) * 32 + 16 * nj + lr];
#pragma unroll
            for (int fr = 0; fr < 4; fr++)
                o[fr][nj] = __builtin_amdgcn_mfma_f32_16x16x32_bf16(pa[fr], vb, o[fr][nj], 0, 0, 0);
        }
    }
#pragma unroll
    for (int fr = 0; fr < 4; fr++)
#pragma unroll
        for (int nj = 0; nj < 2; nj++)
#pragma unroll
            for (int i = 0; i < 4; i++) {
                int t = 16 * fr + 4 * lk + i;
                int grow = rowbase + (t >> 3) * 64 + (t & 7);
                AO[(size_t)grow * 512 + h * 32 + 16 * nj + lr] = f2bf(o[fr][nj][i] * rinv[fr][i]);
            }
}

// ---------- launch ----------
extern "C" void kernel_launch(void* const* d_in, const int* in_sizes, int n_in,
                              void* d_out, int out_size, void* d_ws, size_t ws_size,
                              hipStream_t stream)
{
    const float* x1     = (const float*)d_in[0];
    const float* x2     = (const float*)d_in[1];
    const float* n1w    = (const float*)d_in[2];
    const float* n1b    = (const float*)d_in[3];
    const float* n2w    = (const float*)d_in[4];
    const float* n2b    = (const float*)d_in[5];
    const float* qkv1_w = (const float*)d_in[6];
    const float* qkv1_b = (const float*)d_in[7];
    const float* qkv2_w = (const float*)d_in[8];
    const float* qkv2_b = (const float*)d_in[9];
    const float* rpb    = (const float*)d_in[10];
    const float* proj_w = (const float*)d_in[11];
    const float* proj_b = (const float*)d_in[12];
    float* out = (float*)d_out;

    char* ws = (char*)d_ws;
    const size_t SZ = 67108864;   // 65536*512*2 bytes
    unsigned short* XN1  = (unsigned short*)(ws);
    unsigned short* XN2  = (unsigned short*)(ws + SZ);
    unsigned short* Qb   = (unsigned short*)(ws + 2 * SZ);
    unsigned short* KVb  = (unsigned short*)(ws + 3 * SZ);       // 128MB (K then V)
    unsigned short* WqT  = (unsigned short*)(ws + 5 * SZ);
    unsigned short* WkvT = WqT + 512 * 512;
    unsigned short* WpT  = WkvT + 1024 * 512;
    unsigned short* AO   = XN2;   // XN2 dead after qkv gemm; reuse for attention output

    hipLaunchKernelGGL(ln_kernel,     dim3(32768), dim3(256), 0, stream,
                       x1, x2, n1w, n1b, n2w, n2b, XN1, XN2);
    hipLaunchKernelGGL(wconv_kernel,  dim3(1024),  dim3(256), 0, stream,
                       qkv1_w, qkv2_w, proj_w, WqT, WkvT, WpT);
    hipLaunchKernelGGL(qkv_gemm256,   dim3(1536),  dim3(512), 0, stream,
                       XN1, XN2, WqT, WkvT, qkv1_b, qkv2_b, Qb, KVb);
    hipLaunchKernelGGL(attn_kernel,   dim3(4096),  dim3(256), 0, stream,
                       Qb, KVb, rpb, AO);
    hipLaunchKernelGGL(proj_gemm256,  dim3(512),   dim3(512), 0, stream,
                       AO, WpT, proj_b, x1, out);
}

// Round 7
// 665.925 us; speedup vs baseline: 1.0923x; 1.0150x over previous
//
#include <hip/hip_runtime.h>
#include <hip/hip_bf16.h>

// ---------- types ----------
typedef __attribute__((ext_vector_type(8))) short short8;   // 8 x bf16 (4 VGPR) MFMA frag
typedef __attribute__((ext_vector_type(4))) float f32x4;    // MFMA accumulator

#define SCALE 0.17677669529663687f   // 32^-0.5

__device__ __forceinline__ unsigned short f2bf(float f) {
    union { __hip_bfloat16 b; unsigned short u; } c;
    c.b = __float2bfloat16(f);
    return c.u;
}

__device__ __forceinline__ void gload_lds16(const unsigned short* g, unsigned short* l) {
    __builtin_amdgcn_global_load_lds((const __attribute__((address_space(1))) void*)g,
                                     (__attribute__((address_space(3))) void*)l, 16, 0, 0);
}

// ---------- 1) fused LayerNorm (x1 & x2), fp32 -> bf16 ----------
__global__ __launch_bounds__(256) void ln_kernel(
    const float* __restrict__ x1, const float* __restrict__ x2,
    const float* __restrict__ n1w, const float* __restrict__ n1b,
    const float* __restrict__ n2w, const float* __restrict__ n2b,
    unsigned short* __restrict__ xn1, unsigned short* __restrict__ xn2)
{
    int lane = threadIdx.x & 63;
    int row  = blockIdx.x * 4 + (threadIdx.x >> 6);      // 0..131071
    const float* src; const float* w; const float* b; unsigned short* dst;
    if (row < 65536) {
        src = x1 + (size_t)row * 512; w = n1w; b = n1b; dst = xn1 + (size_t)row * 512;
    } else {
        size_t r = (size_t)(row - 65536);
        src = x2 + r * 512; w = n2w; b = n2b; dst = xn2 + r * 512;
    }
    float4 v0 = *(const float4*)(src + lane * 4);
    float4 v1 = *(const float4*)(src + 256 + lane * 4);
    float s = v0.x + v0.y + v0.z + v0.w + v1.x + v1.y + v1.z + v1.w;
    float q = v0.x*v0.x + v0.y*v0.y + v0.z*v0.z + v0.w*v0.w
            + v1.x*v1.x + v1.y*v1.y + v1.z*v1.z + v1.w*v1.w;
#pragma unroll
    for (int m = 1; m < 64; m <<= 1) { s += __shfl_xor(s, m); q += __shfl_xor(q, m); }
    float mu  = s * (1.0f / 512.0f);
    float var = q * (1.0f / 512.0f) - mu * mu;
    float rs  = rsqrtf(var + 1e-5f);
    float4 w0 = *(const float4*)(w + lane * 4);
    float4 w1 = *(const float4*)(w + 256 + lane * 4);
    float4 b0 = *(const float4*)(b + lane * 4);
    float4 b1 = *(const float4*)(b + 256 + lane * 4);
    ushort4 o0, o1;
    o0.x = f2bf((v0.x - mu) * rs * w0.x + b0.x);
    o0.y = f2bf((v0.y - mu) * rs * w0.y + b0.y);
    o0.z = f2bf((v0.z - mu) * rs * w0.z + b0.z);
    o0.w = f2bf((v0.w - mu) * rs * w0.w + b0.w);
    o1.x = f2bf((v1.x - mu) * rs * w1.x + b1.x);
    o1.y = f2bf((v1.y - mu) * rs * w1.y + b1.y);
    o1.z = f2bf((v1.z - mu) * rs * w1.z + b1.z);
    o1.w = f2bf((v1.w - mu) * rs * w1.w + b1.w);
    *(ushort4*)(dst + lane * 4)       = o0;
    *(ushort4*)(dst + 256 + lane * 4) = o1;
}

// ---------- 2) weight transpose + fp32->bf16 ----------
__global__ __launch_bounds__(256) void wconv_kernel(
    const float* __restrict__ qkv1_w, const float* __restrict__ qkv2_w,
    const float* __restrict__ proj_w,
    unsigned short* __restrict__ WqT, unsigned short* __restrict__ WkvT,
    unsigned short* __restrict__ WpT)
{
    __shared__ float tile[32][33];
    int t = blockIdx.x;
    const float* src; int ldin, c0, tn, tk; unsigned short* dst;
    if (t < 256)      { src = qkv2_w; ldin = 1536; c0 = 0;   dst = WqT;  tn = t >> 4;        tk = t & 15; }
    else if (t < 768) { int u = t - 256; src = qkv1_w; ldin = 1536; c0 = 512; dst = WkvT; tn = u >> 4; tk = u & 15; }
    else              { int u = t - 768; src = proj_w; ldin = 512;  c0 = 0;   dst = WpT;  tn = u >> 4; tk = u & 15; }
    int lx = threadIdx.x & 31, ly = threadIdx.x >> 5;   // ly 0..7
#pragma unroll
    for (int i = 0; i < 4; i++)
        tile[ly + i * 8][lx] = src[(size_t)(tk * 32 + ly + i * 8) * ldin + c0 + tn * 32 + lx];
    __syncthreads();
#pragma unroll
    for (int i = 0; i < 4; i++)
        dst[(size_t)(tn * 32 + ly + i * 8) * 512 + tk * 32 + lx] = f2bf(tile[lx][ly + i * 8]);
}

// =================== 256x256 phased GEMM core (T2+T3+T4+T5) ===================
// Per K-tile (BK=64): vmcnt(8) -> bar1 (tile t published; loads-ledger:
// drained = issued-8 = tiles 0..t exactly) -> 24 ds_reads (s0+s1; s1 reads
// free to hoist over s0 MFMAs) -> 2x32 MFMA (setprio) -> bar2 -> stage tile
// t+2 (both halves; WAR-safe: all waves' reads done at bar2, writes land later).

__device__ __forceinline__ void stage_unit(
    unsigned short* lds, const unsigned short* A, const unsigned short* W,
    int tile, int s, int wv, int sr, int sq, int dst_lane)
{
    int buf = (tile & 1) << 15;           // 32768 elements per K-tile buffer
    int k0  = tile * 64 + s * 32;
#pragma unroll
    for (int i = 0; i < 2; i++) {
        int R   = i * 8 + wv;             // subtile row 0..15
        int sub = (R * 2 + s) << 9;       // subtile offset (elements)
        gload_lds16(A + (size_t)(R * 16 + sr) * 512 + k0 + sq * 8,
                    lds + buf + sub + dst_lane);
        gload_lds16(W + (size_t)(R * 16 + sr) * 512 + k0 + sq * 8,
                    lds + buf + 16384 + sub + dst_lane);
    }
}

template<bool LAST, bool DOST>
__device__ __forceinline__ void gtile(
    unsigned short* lds, const unsigned short* A, const unsigned short* W,
    f32x4 (&acc)[8][4], int tile, int st_t,
    int wr, int wc, int wv, int rdoff, int sr, int sq, int dst_lane)
{
    if constexpr (LAST) asm volatile("s_waitcnt vmcnt(0)" ::: "memory");
    else                asm volatile("s_waitcnt vmcnt(8)" ::: "memory");
    __builtin_amdgcn_s_barrier();
    __builtin_amdgcn_sched_barrier(0);
    int buf = (tile & 1) << 15;
    short8 a0[8], b0[4], a1[8], b1[4];
#pragma unroll
    for (int mi = 0; mi < 8; mi++)
        a0[mi] = *(const short8*)(lds + buf + (((wr * 8 + mi) * 2 + 0) << 9) + rdoff);
#pragma unroll
    for (int ni = 0; ni < 4; ni++)
        b0[ni] = *(const short8*)(lds + buf + 16384 + (((wc * 4 + ni) * 2 + 0) << 9) + rdoff);
    __builtin_amdgcn_s_setprio(1);
#pragma unroll
    for (int mi = 0; mi < 8; mi++)
#pragma unroll
        for (int ni = 0; ni < 4; ni++)
            acc[mi][ni] = __builtin_amdgcn_mfma_f32_16x16x32_bf16(a0[mi], b0[ni], acc[mi][ni], 0, 0, 0);
    __builtin_amdgcn_s_setprio(0);
#pragma unroll
    for (int mi = 0; mi < 8; mi++)
        a1[mi] = *(const short8*)(lds + buf + (((wr * 8 + mi) * 2 + 1) << 9) + rdoff);
#pragma unroll
    for (int ni = 0; ni < 4; ni++)
        b1[ni] = *(const short8*)(lds + buf + 16384 + (((wc * 4 + ni) * 2 + 1) << 9) + rdoff);
    __builtin_amdgcn_s_setprio(1);
#pragma unroll
    for (int mi = 0; mi < 8; mi++)
#pragma unroll
        for (int ni = 0; ni < 4; ni++)
            acc[mi][ni] = __builtin_amdgcn_mfma_f32_16x16x32_bf16(a1[mi], b1[ni], acc[mi][ni], 0, 0, 0);
    __builtin_amdgcn_s_setprio(0);
    __builtin_amdgcn_sched_barrier(0);
    __builtin_amdgcn_s_barrier();
    __builtin_amdgcn_sched_barrier(0);
    if constexpr (DOST) {
        stage_unit(lds, A, W, st_t, 0, wv, sr, sq, dst_lane);
        stage_unit(lds, A, W, st_t, 1, wv, sr, sq, dst_lane);
    }
}

__device__ __forceinline__ void gemm256(
    unsigned short* lds, const unsigned short* A, const unsigned short* W,
    f32x4 (&acc)[8][4])
{
    int tid = threadIdx.x, lane = tid & 63, wv = tid >> 6;
    int wr = wv >> 2, wc = wv & 3;
    int lr = lane & 15, lk = lane >> 4;
    int rdoff    = lr * 32 + ((lk ^ ((lr >> 1) & 3)) << 3);  // swizzled frag addr
    int sr       = lane >> 2;                                 // stage row in subtile
    int sq       = (lane & 3) ^ ((sr >> 1) & 3);              // inverse-swz src chunk
    int dst_lane = lane * 8;                                  // linear LDS dest

    // prologue: fully stage K-tiles 0 and 1 (16 loads in flight)
    stage_unit(lds, A, W, 0, 0, wv, sr, sq, dst_lane);
    stage_unit(lds, A, W, 0, 1, wv, sr, sq, dst_lane);
    stage_unit(lds, A, W, 1, 0, wv, sr, sq, dst_lane);
    stage_unit(lds, A, W, 1, 1, wv, sr, sq, dst_lane);

    gtile<false, true >(lds, A, W, acc, 0, 2, wr, wc, wv, rdoff, sr, sq, dst_lane);
    gtile<false, true >(lds, A, W, acc, 1, 3, wr, wc, wv, rdoff, sr, sq, dst_lane);
    gtile<false, true >(lds, A, W, acc, 2, 4, wr, wc, wv, rdoff, sr, sq, dst_lane);
    gtile<false, true >(lds, A, W, acc, 3, 5, wr, wc, wv, rdoff, sr, sq, dst_lane);
    gtile<false, true >(lds, A, W, acc, 4, 6, wr, wc, wv, rdoff, sr, sq, dst_lane);
    gtile<false, true >(lds, A, W, acc, 5, 7, wr, wc, wv, rdoff, sr, sq, dst_lane);
    gtile<false, false>(lds, A, W, acc, 6, 0, wr, wc, wv, rdoff, sr, sq, dst_lane);
    gtile<true , false>(lds, A, W, acc, 7, 0, wr, wc, wv, rdoff, sr, sq, dst_lane);
}

// ---------- 3) QKV GEMM: 1536 blocks (256 mb x 6 nb). nb<2 -> Q, else KV ----------
__global__ __launch_bounds__(512) void qkv_gemm256(
    const unsigned short* __restrict__ XN1, const unsigned short* __restrict__ XN2,
    const unsigned short* __restrict__ WqT, const unsigned short* __restrict__ WkvT,
    const float* __restrict__ qkv1_b, const float* __restrict__ qkv2_b,
    unsigned short* __restrict__ Qb, unsigned short* __restrict__ KVb)
{
    __shared__ unsigned short lds[65536];   // 128 KiB
    int bid = blockIdx.x;
    int wg  = (bid & 7) * 192 + (bid >> 3);    // XCD-bijective (1536 = 8*192)
    int mb  = wg / 6, nb = wg % 6;             // 6 n-tiles of one m-tile per XCD chunk
    f32x4 acc[8][4];
#pragma unroll
    for (int mi = 0; mi < 8; mi++)
#pragma unroll
        for (int ni = 0; ni < 4; ni++) { f32x4 z = {0.f,0.f,0.f,0.f}; acc[mi][ni] = z; }
    const unsigned short* A; const unsigned short* W;
    if (nb < 2) { A = XN2 + (size_t)mb * 256 * 512; W = WqT  + (size_t)nb * 256 * 512; }
    else        { A = XN1 + (size_t)mb * 256 * 512; W = WkvT + (size_t)(nb - 2) * 256 * 512; }
    gemm256(lds, A, W, acc);

    int lane = threadIdx.x & 63, wv = threadIdx.x >> 6;
    int wr = wv >> 2, wc = wv & 3, lr = lane & 15, lk = lane >> 4;
    int base_m = mb * 256 + wr * 128;
    if (nb < 2) {
#pragma unroll
        for (int ni = 0; ni < 4; ni++) {
            int col = nb * 256 + wc * 64 + ni * 16 + lr;
            float bias = qkv2_b[col];
#pragma unroll
            for (int mi = 0; mi < 8; mi++)
#pragma unroll
                for (int ii = 0; ii < 4; ii++) {
                    int row = base_m + mi * 16 + lk * 4 + ii;
                    Qb[(size_t)row * 512 + col] = f2bf((acc[mi][ni][ii] + bias) * SCALE);
                }
        }
    } else {
#pragma unroll
        for (int ni = 0; ni < 4; ni++) {
            int col = (nb - 2) * 256 + wc * 64 + ni * 16 + lr;   // 0..1023: K then V
            float bias = qkv1_b[512 + col];
#pragma unroll
            for (int mi = 0; mi < 8; mi++)
#pragma unroll
                for (int ii = 0; ii < 4; ii++) {
                    int row = base_m + mi * 16 + lk * 4 + ii;
                    KVb[(size_t)row * 1024 + col] = f2bf(acc[mi][ni][ii] + bias);
                }
        }
    }
}

// ---------- 5) proj GEMM + bias + residual: 512 blocks (256 mb x 2 nb) ----------
__global__ __launch_bounds__(512) void proj_gemm256(
    const unsigned short* __restrict__ AO, const unsigned short* __restrict__ WpT,
    const float* __restrict__ proj_b, const float* __restrict__ x1,
    float* __restrict__ out)
{
    __shared__ unsigned short lds[65536];
    int bid = blockIdx.x;
    int wg  = (bid & 7) * 64 + (bid >> 3);     // XCD-bijective (512 = 8*64)
    int mb  = wg >> 1, nb = wg & 1;
    f32x4 acc[8][4];
#pragma unroll
    for (int mi = 0; mi < 8; mi++)
#pragma unroll
        for (int ni = 0; ni < 4; ni++) { f32x4 z = {0.f,0.f,0.f,0.f}; acc[mi][ni] = z; }
    gemm256(lds, AO + (size_t)mb * 256 * 512, WpT + (size_t)nb * 256 * 512, acc);

    int lane = threadIdx.x & 63, wv = threadIdx.x >> 6;
    int wr = wv >> 2, wc = wv & 3, lr = lane & 15, lk = lane >> 4;
    int base_m = mb * 256 + wr * 128;
#pragma unroll
    for (int ni = 0; ni < 4; ni++) {
        int col = nb * 256 + wc * 64 + ni * 16 + lr;
        float bias = proj_b[col];
#pragma unroll
        for (int mi = 0; mi < 8; mi++)
#pragma unroll
            for (int ii = 0; ii < 4; ii++) {
                int row = base_m + mi * 16 + lk * 4 + ii;
                out[(size_t)row * 512 + col] = acc[mi][ni][ii] + bias + x1[(size_t)row * 512 + col];
            }
    }
}

// ---------- 4a) bias table precompute in MFMA C-frag layout ----------
// biasC[h][fr][fc][lane][i] = rpb[REL(16fr+4lk+i, 16fc+lr)*16 + h]  (fp32, 256KB)
__global__ __launch_bounds__(256) void bias_pre(
    const float* __restrict__ rpb, float* __restrict__ biasC)
{
    int h = blockIdx.x;                    // 0..15
    int lane = threadIdx.x & 63;
    int fr = threadIdx.x >> 6;             // 0..3
    int lk = lane >> 4, lr = lane & 15;
#pragma unroll
    for (int fc = 0; fc < 4; fc++) {
        float4 v;
#pragma unroll
        for (int i = 0; i < 4; i++) {
            int n = 16 * fr + 4 * lk + i;
            int m = 16 * fc + lr;
            int idx = ((n >> 3) - (m >> 3) + 7) * 15 + (n & 7) - (m & 7) + 7;
            (&v.x)[i] = rpb[idx * 16 + h];
        }
        *(float4*)(biasC + (((h * 4 + fr) * 4 + fc) << 8) + (lane << 2)) = v;
    }
}

// ---------- 4) windowed cross-attention: one wave per (window, head) ----------
__global__ __launch_bounds__(256) void attn_kernel(
    const unsigned short* __restrict__ Qb, const unsigned short* __restrict__ KVb,
    const float* __restrict__ biasC, unsigned short* __restrict__ AO)
{
    __shared__ unsigned short sV[4][64 * 32];
    __shared__ unsigned short sP[4][64 * 64];
    int wv = threadIdx.x >> 6, lane = threadIdx.x & 63;
    int lr = lane & 15, lk = lane >> 4;
    int u = blockIdx.x * 4 + wv;           // 0..16383
    int win = u >> 4, h = u & 15;
    int b = win >> 6, wi = win & 63;
    int rowbase = b * 4096 + (wi >> 3) * 512 + (wi & 7) * 8;
    unsigned short* myV = sV[wv];
    unsigned short* myP = sP[wv];

#pragma unroll
    for (int i = 0; i < 4; i++) {
        int c = i * 64 + lane;             // 16B chunk id, 0..255
        int t = c >> 2, cc = c & 3;
        int grow = rowbase + (t >> 3) * 64 + (t & 7);
        *(short8*)(myV + t * 32 + cc * 8) =
            *(const short8*)(KVb + (size_t)grow * 1024 + 512 + h * 32 + cc * 8);
    }
    short8 qf[4], kf[4];
#pragma unroll
    for (int fr = 0; fr < 4; fr++) {
        int t = 16 * fr + lr;
        int grow = rowbase + (t >> 3) * 64 + (t & 7);
        qf[fr] = *(const short8*)(Qb  + (size_t)grow * 512  + h * 32 + lk * 8);
        kf[fr] = *(const short8*)(KVb + (size_t)grow * 1024 + h * 32 + lk * 8);
    }
    f32x4 s[4][4];
#pragma unroll
    for (int fr = 0; fr < 4; fr++)
#pragma unroll
        for (int fc = 0; fc < 4; fc++) { f32x4 z = {0.f,0.f,0.f,0.f}; s[fr][fc] = z; }
#pragma unroll
    for (int fr = 0; fr < 4; fr++)
#pragma unroll
        for (int fc = 0; fc < 4; fc++)
            s[fr][fc] = __builtin_amdgcn_mfma_f32_16x16x32_bf16(qf[fr], kf[fc], s[fr][fc], 0, 0, 0);

    const float* bch = biasC + (h << 12);   // h * 4096
    float rinv[4][4];
#pragma unroll
    for (int fr = 0; fr < 4; fr++) {
        f32x4 bb[4];
#pragma unroll
        for (int fc = 0; fc < 4; fc++)
            bb[fc] = *(const f32x4*)(bch + (((fr << 2) + fc) << 8) + (lane << 2));
#pragma unroll
        for (int i = 0; i < 4; i++) {
            int n = 16 * fr + 4 * lk + i;
#pragma unroll
            for (int fc = 0; fc < 4; fc++)
                s[fr][fc][i] += bb[fc][i];
            float v = fmaxf(fmaxf(s[fr][0][i], s[fr][1][i]), fmaxf(s[fr][2][i], s[fr][3][i]));
            v = fmaxf(v, __shfl_xor(v, 1)); v = fmaxf(v, __shfl_xor(v, 2));
            v = fmaxf(v, __shfl_xor(v, 4)); v = fmaxf(v, __shfl_xor(v, 8));
            float sum = 0.f;
#pragma unroll
            for (int fc = 0; fc < 4; fc++) {
                float e = __expf(s[fr][fc][i] - v);
                s[fr][fc][i] = e; sum += e;
            }
            sum += __shfl_xor(sum, 1); sum += __shfl_xor(sum, 2);
            sum += __shfl_xor(sum, 4); sum += __shfl_xor(sum, 8);
            rinv[fr][i] = 1.0f / sum;
#pragma unroll
            for (int fc = 0; fc < 4; fc++) {
                int m = 16 * fc + lr;
                int chunk = (m >> 3) ^ (n & 7);
                myP[n * 64 + chunk * 8 + (m & 7)] = f2bf(s[fr][fc][i]);
            }
        }
    }
    __syncthreads();

    f32x4 o[4][2];
#pragma unroll
    for (int fr = 0; fr < 4; fr++)
#pragma unroll
        for (int nj = 0; nj < 2; nj++) { f32x4 z = {0.f,0.f,0.f,0.f}; o[fr][nj] = z; }
#pragma unroll
    for (int mk = 0; mk < 2; mk++) {
        short8 pa[4];
#pragma unroll
        for (int fr = 0; fr < 4; fr++) {
            int n = 16 * fr + lr;
            int chunk = (4 * mk + lk) ^ (n & 7);
            pa[fr] = *(const short8*)(myP + n * 64 + chunk * 8);
        }
#pragma unroll
        for (int nj = 0; nj < 2; nj++) {
            short8 vb;
#pragma unroll
            for (int j = 0; j < 8; j++)
                vb[j] = (short)myV[(32 * mk + 8 * lk + j) * 32 + 16 * nj + lr];
#pragma unroll
            for (int fr = 0; fr < 4; fr++)
                o[fr][nj] = __builtin_amdgcn_mfma_f32_16x16x32_bf16(pa[fr], vb, o[fr][nj], 0, 0, 0);
        }
    }
#pragma unroll
    for (int fr = 0; fr < 4; fr++)
#pragma unroll
        for (int nj = 0; nj < 2; nj++)
#pragma unroll
            for (int i = 0; i < 4; i++) {
                int t = 16 * fr + 4 * lk + i;
                int grow = rowbase + (t >> 3) * 64 + (t & 7);
                AO[(size_t)grow * 512 + h * 32 + 16 * nj + lr] = f2bf(o[fr][nj][i] * rinv[fr][i]);
            }
}

// ---------- launch ----------
extern "C" void kernel_launch(void* const* d_in, const int* in_sizes, int n_in,
                              void* d_out, int out_size, void* d_ws, size_t ws_size,
                              hipStream_t stream)
{
    const float* x1     = (const float*)d_in[0];
    const float* x2     = (const float*)d_in[1];
    const float* n1w    = (const float*)d_in[2];
    const float* n1b    = (const float*)d_in[3];
    const float* n2w    = (const float*)d_in[4];
    const float* n2b    = (const float*)d_in[5];
    const float* qkv1_w = (const float*)d_in[6];
    const float* qkv1_b = (const float*)d_in[7];
    const float* qkv2_w = (const float*)d_in[8];
    const float* qkv2_b = (const float*)d_in[9];
    const float* rpb    = (const float*)d_in[10];
    const float* proj_w = (const float*)d_in[11];
    const float* proj_b = (const float*)d_in[12];
    float* out = (float*)d_out;

    char* ws = (char*)d_ws;
    const size_t SZ = 67108864;   // 65536*512*2 bytes
    unsigned short* XN1  = (unsigned short*)(ws);
    unsigned short* XN2  = (unsigned short*)(ws + SZ);
    unsigned short* Qb   = (unsigned short*)(ws + 2 * SZ);
    unsigned short* KVb  = (unsigned short*)(ws + 3 * SZ);       // 128MB (K then V)
    unsigned short* WqT  = (unsigned short*)(ws + 5 * SZ);
    unsigned short* WkvT = WqT + 512 * 512;
    unsigned short* WpT  = WkvT + 1024 * 512;
    unsigned short* AO   = XN2;   // XN2 dead after qkv gemm; reuse for attention output
    float* biasC = (float*)ws;    // aliases XN1 (dead after qkv); 256 KB, written post-qkv

    hipLaunchKernelGGL(ln_kernel,     dim3(32768), dim3(256), 0, stream,
                       x1, x2, n1w, n1b, n2w, n2b, XN1, XN2);
    hipLaunchKernelGGL(wconv_kernel,  dim3(1024),  dim3(256), 0, stream,
                       qkv1_w, qkv2_w, proj_w, WqT, WkvT, WpT);
    hipLaunchKernelGGL(qkv_gemm256,   dim3(1536),  dim3(512), 0, stream,
                       XN1, XN2, WqT, WkvT, qkv1_b, qkv2_b, Qb, KVb);
    hipLaunchKernelGGL(bias_pre,      dim3(16),    dim3(256), 0, stream,
                       rpb, biasC);
    hipLaunchKernelGGL(attn_kernel,   dim3(4096),  dim3(256), 0, stream,
                       Qb, KVb, biasC, AO);
    hipLaunchKernelGGL(proj_gemm256,  dim3(512),   dim3(512), 0, stream,
                       AO, WpT, proj_b, x1, out);
}

// Round 9
// 653.477 us; speedup vs baseline: 1.1131x; 1.0190x over previous
//
#include <hip/hip_runtime.h>
#include <hip/hip_bf16.h>

// ---------- types ----------
typedef __attribute__((ext_vector_type(8))) short short8;   // 8 x bf16 (4 VGPR) MFMA frag
typedef __attribute__((ext_vector_type(4))) float f32x4;    // MFMA accumulator

#define SCALE 0.17677669529663687f   // 32^-0.5

__device__ __forceinline__ unsigned short f2bf(float f) {
    union { __hip_bfloat16 b; unsigned short u; } c;
    c.b = __float2bfloat16(f);
    return c.u;
}

__device__ __forceinline__ void gload_lds16(const unsigned short* g, unsigned short* l) {
    __builtin_amdgcn_global_load_lds((const __attribute__((address_space(1))) void*)g,
                                     (__attribute__((address_space(3))) void*)l, 16, 0, 0);
}

// ---------- 1) fused LayerNorm (x1 & x2), fp32 -> bf16 ----------
__global__ __launch_bounds__(256) void ln_kernel(
    const float* __restrict__ x1, const float* __restrict__ x2,
    const float* __restrict__ n1w, const float* __restrict__ n1b,
    const float* __restrict__ n2w, const float* __restrict__ n2b,
    unsigned short* __restrict__ xn1, unsigned short* __restrict__ xn2)
{
    int lane = threadIdx.x & 63;
    int row  = blockIdx.x * 4 + (threadIdx.x >> 6);      // 0..131071
    const float* src; const float* w; const float* b; unsigned short* dst;
    if (row < 65536) {
        src = x1 + (size_t)row * 512; w = n1w; b = n1b; dst = xn1 + (size_t)row * 512;
    } else {
        size_t r = (size_t)(row - 65536);
        src = x2 + r * 512; w = n2w; b = n2b; dst = xn2 + r * 512;
    }
    float4 v0 = *(const float4*)(src + lane * 4);
    float4 v1 = *(const float4*)(src + 256 + lane * 4);
    float s = v0.x + v0.y + v0.z + v0.w + v1.x + v1.y + v1.z + v1.w;
    float q = v0.x*v0.x + v0.y*v0.y + v0.z*v0.z + v0.w*v0.w
            + v1.x*v1.x + v1.y*v1.y + v1.z*v1.z + v1.w*v1.w;
#pragma unroll
    for (int m = 1; m < 64; m <<= 1) { s += __shfl_xor(s, m); q += __shfl_xor(q, m); }
    float mu  = s * (1.0f / 512.0f);
    float var = q * (1.0f / 512.0f) - mu * mu;
    float rs  = rsqrtf(var + 1e-5f);
    float4 w0 = *(const float4*)(w + lane * 4);
    float4 w1 = *(const float4*)(w + 256 + lane * 4);
    float4 b0 = *(const float4*)(b + lane * 4);
    float4 b1 = *(const float4*)(b + 256 + lane * 4);
    ushort4 o0, o1;
    o0.x = f2bf((v0.x - mu) * rs * w0.x + b0.x);
    o0.y = f2bf((v0.y - mu) * rs * w0.y + b0.y);
    o0.z = f2bf((v0.z - mu) * rs * w0.z + b0.z);
    o0.w = f2bf((v0.w - mu) * rs * w0.w + b0.w);
    o1.x = f2bf((v1.x - mu) * rs * w1.x + b1.x);
    o1.y = f2bf((v1.y - mu) * rs * w1.y + b1.y);
    o1.z = f2bf((v1.z - mu) * rs * w1.z + b1.z);
    o1.w = f2bf((v1.w - mu) * rs * w1.w + b1.w);
    *(ushort4*)(dst + lane * 4)       = o0;
    *(ushort4*)(dst + 256 + lane * 4) = o1;
}

// ---------- 2) weight transpose + fp32->bf16 ----------
__global__ __launch_bounds__(256) void wconv_kernel(
    const float* __restrict__ qkv1_w, const float* __restrict__ qkv2_w,
    const float* __restrict__ proj_w,
    unsigned short* __restrict__ WqT, unsigned short* __restrict__ WkvT,
    unsigned short* __restrict__ WpT)
{
    __shared__ float tile[32][33];
    int t = blockIdx.x;
    const float* src; int ldin, c0, tn, tk; unsigned short* dst;
    if (t < 256)      { src = qkv2_w; ldin = 1536; c0 = 0;   dst = WqT;  tn = t >> 4;        tk = t & 15; }
    else if (t < 768) { int u = t - 256; src = qkv1_w; ldin = 1536; c0 = 512; dst = WkvT; tn = u >> 4; tk = u & 15; }
    else              { int u = t - 768; src = proj_w; ldin = 512;  c0 = 0;   dst = WpT;  tn = u >> 4; tk = u & 15; }
    int lx = threadIdx.x & 31, ly = threadIdx.x >> 5;   // ly 0..7
#pragma unroll
    for (int i = 0; i < 4; i++)
        tile[ly + i * 8][lx] = src[(size_t)(tk * 32 + ly + i * 8) * ldin + c0 + tn * 32 + lx];
    __syncthreads();
#pragma unroll
    for (int i = 0; i < 4; i++)
        dst[(size_t)(tn * 32 + ly + i * 8) * 512 + tk * 32 + lx] = f2bf(tile[lx][ly + i * 8]);
}

// =================== 256x256 phased GEMM core ===================
// Per K-tile t: vmcnt(8)->bar1 (tile t published) -> 24 ds_reads (s0+s1; the
// s1 reads stay in flight under MFMA_s0 via compiler lgkmcnt(12)) ->
// MFMA_s0 x32 -> lgkmcnt(0) -> bar2 (ALL waves' reads of tile t complete) ->
// stage tile t+2 (8 loads, WAR-safe behind bar2) -> MFMA_s1 x32 (overlaps
// the stage issue). 1 vmcnt + 2 barriers per K-tile; vmcnt never 0 mid-loop.

__device__ __forceinline__ void stage_unit(
    unsigned short* lds, const unsigned short* A, const unsigned short* W,
    int tile, int s, int wv, int sr, int sq, int dst_lane)
{
    int buf = (tile & 1) << 15;           // 32768 elements per K-tile buffer
    int k0  = tile * 64 + s * 32;
#pragma unroll
    for (int i = 0; i < 2; i++) {
        int R   = i * 8 + wv;             // subtile row 0..15
        int sub = (R * 2 + s) << 9;       // subtile offset (elements)
        gload_lds16(A + (size_t)(R * 16 + sr) * 512 + k0 + sq * 8,
                    lds + buf + sub + dst_lane);
        gload_lds16(W + (size_t)(R * 16 + sr) * 512 + k0 + sq * 8,
                    lds + buf + 16384 + sub + dst_lane);
    }
}

template<bool LAST, bool DOST>
__device__ __forceinline__ void gtile(
    unsigned short* lds, const unsigned short* A, const unsigned short* W,
    f32x4 (&acc)[8][4], int tile, int st_t,
    int wr, int wc, int wv, int rdoff, int sr, int sq, int dst_lane)
{
    if constexpr (LAST) asm volatile("s_waitcnt vmcnt(0)" ::: "memory");
    else                asm volatile("s_waitcnt vmcnt(8)" ::: "memory");
    __builtin_amdgcn_s_barrier();
    __builtin_amdgcn_sched_barrier(0);
    int buf = (tile & 1) << 15;
    short8 a0[8], b0[4], a1[8], b1[4];
#pragma unroll
    for (int mi = 0; mi < 8; mi++)
        a0[mi] = *(const short8*)(lds + buf + (((wr * 8 + mi) * 2 + 0) << 9) + rdoff);
#pragma unroll
    for (int ni = 0; ni < 4; ni++)
        b0[ni] = *(const short8*)(lds + buf + 16384 + (((wc * 4 + ni) * 2 + 0) << 9) + rdoff);
#pragma unroll
    for (int mi = 0; mi < 8; mi++)
        a1[mi] = *(const short8*)(lds + buf + (((wr * 8 + mi) * 2 + 1) << 9) + rdoff);
#pragma unroll
    for (int ni = 0; ni < 4; ni++)
        b1[ni] = *(const short8*)(lds + buf + 16384 + (((wc * 4 + ni) * 2 + 1) << 9) + rdoff);
    __builtin_amdgcn_s_setprio(1);
#pragma unroll
    for (int mi = 0; mi < 8; mi++)
#pragma unroll
        for (int ni = 0; ni < 4; ni++)
            acc[mi][ni] = __builtin_amdgcn_mfma_f32_16x16x32_bf16(a0[mi], b0[ni], acc[mi][ni], 0, 0, 0);
    __builtin_amdgcn_s_setprio(0);
    asm volatile("s_waitcnt lgkmcnt(0)" ::: "memory");
    __builtin_amdgcn_sched_barrier(0);
    __builtin_amdgcn_s_barrier();
    __builtin_amdgcn_sched_barrier(0);
    if constexpr (DOST) {
        stage_unit(lds, A, W, st_t, 0, wv, sr, sq, dst_lane);
        stage_unit(lds, A, W, st_t, 1, wv, sr, sq, dst_lane);
    }
    __builtin_amdgcn_sched_barrier(0);    // keep MFMA_s1 after the stage issue
    __builtin_amdgcn_s_setprio(1);
#pragma unroll
    for (int mi = 0; mi < 8; mi++)
#pragma unroll
        for (int ni = 0; ni < 4; ni++)
            acc[mi][ni] = __builtin_amdgcn_mfma_f32_16x16x32_bf16(a1[mi], b1[ni], acc[mi][ni], 0, 0, 0);
    __builtin_amdgcn_s_setprio(0);
}

__device__ __forceinline__ void gemm256(
    unsigned short* lds, const unsigned short* A, const unsigned short* W,
    f32x4 (&acc)[8][4])
{
    int tid = threadIdx.x, lane = tid & 63, wv = tid >> 6;
    int wr = wv >> 2, wc = wv & 3;
    int lr = lane & 15, lk = lane >> 4;
    int rdoff    = lr * 32 + ((lk ^ ((lr >> 1) & 3)) << 3);  // swizzled frag addr
    int sr       = lane >> 2;                                 // stage row in subtile
    int sq       = (lane & 3) ^ ((sr >> 1) & 3);              // inverse-swz src chunk
    int dst_lane = lane * 8;                                  // linear LDS dest

    // prologue: fully stage K-tiles 0 and 1 (16 loads in flight)
    stage_unit(lds, A, W, 0, 0, wv, sr, sq, dst_lane);
    stage_unit(lds, A, W, 0, 1, wv, sr, sq, dst_lane);
    stage_unit(lds, A, W, 1, 0, wv, sr, sq, dst_lane);
    stage_unit(lds, A, W, 1, 1, wv, sr, sq, dst_lane);

    gtile<false, true >(lds, A, W, acc, 0, 2, wr, wc, wv, rdoff, sr, sq, dst_lane);
    gtile<false, true >(lds, A, W, acc, 1, 3, wr, wc, wv, rdoff, sr, sq, dst_lane);
    gtile<false, true >(lds, A, W, acc, 2, 4, wr, wc, wv, rdoff, sr, sq, dst_lane);
    gtile<false, true >(lds, A, W, acc, 3, 5, wr, wc, wv, rdoff, sr, sq, dst_lane);
    gtile<false, true >(lds, A, W, acc, 4, 6, wr, wc, wv, rdoff, sr, sq, dst_lane);
    gtile<false, true >(lds, A, W, acc, 5, 7, wr, wc, wv, rdoff, sr, sq, dst_lane);
    gtile<false, false>(lds, A, W, acc, 6, 0, wr, wc, wv, rdoff, sr, sq, dst_lane);
    gtile<true , false>(lds, A, W, acc, 7, 0, wr, wc, wv, rdoff, sr, sq, dst_lane);
}

// ---------- 3) QKV GEMM: 1536 blocks (256 mb x 6 nb). nb<2 -> Q, else KV ----------
__global__ __launch_bounds__(512) void qkv_gemm256(
    const unsigned short* __restrict__ XN1, const unsigned short* __restrict__ XN2,
    const unsigned short* __restrict__ WqT, const unsigned short* __restrict__ WkvT,
    const float* __restrict__ qkv1_b, const float* __restrict__ qkv2_b,
    unsigned short* __restrict__ Qb, unsigned short* __restrict__ KVb)
{
    __shared__ unsigned short lds[65536];   // 128 KiB
    int bid = blockIdx.x;
    int wg  = (bid & 7) * 192 + (bid >> 3);    // XCD-bijective (1536 = 8*192)
    int mb  = wg / 6, nb = wg % 6;             // 6 n-tiles of one m-tile per XCD chunk
    f32x4 acc[8][4];
#pragma unroll
    for (int mi = 0; mi < 8; mi++)
#pragma unroll
        for (int ni = 0; ni < 4; ni++) { f32x4 z = {0.f,0.f,0.f,0.f}; acc[mi][ni] = z; }
    const unsigned short* A; const unsigned short* W;
    if (nb < 2) { A = XN2 + (size_t)mb * 256 * 512; W = WqT  + (size_t)nb * 256 * 512; }
    else        { A = XN1 + (size_t)mb * 256 * 512; W = WkvT + (size_t)(nb - 2) * 256 * 512; }
    gemm256(lds, A, W, acc);

    int lane = threadIdx.x & 63, wv = threadIdx.x >> 6;
    int wr = wv >> 2, wc = wv & 3, lr = lane & 15, lk = lane >> 4;
    int base_m = mb * 256 + wr * 128;
    if (nb < 2) {
#pragma unroll
        for (int ni = 0; ni < 4; ni++) {
            int col = nb * 256 + wc * 64 + ni * 16 + lr;
            float bias = qkv2_b[col];
#pragma unroll
            for (int mi = 0; mi < 8; mi++)
#pragma unroll
                for (int ii = 0; ii < 4; ii++) {
                    int row = base_m + mi * 16 + lk * 4 + ii;
                    Qb[(size_t)row * 512 + col] = f2bf((acc[mi][ni][ii] + bias) * SCALE);
                }
        }
    } else {
#pragma unroll
        for (int ni = 0; ni < 4; ni++) {
            int col = (nb - 2) * 256 + wc * 64 + ni * 16 + lr;   // 0..1023: K then V
            float bias = qkv1_b[512 + col];
#pragma unroll
            for (int mi = 0; mi < 8; mi++)
#pragma unroll
                for (int ii = 0; ii < 4; ii++) {
                    int row = base_m + mi * 16 + lk * 4 + ii;
                    KVb[(size_t)row * 1024 + col] = f2bf(acc[mi][ni][ii] + bias);
                }
        }
    }
}

// ---------- 5) proj GEMM + bias + residual: 512 blocks (256 mb x 2 nb) ----------
__global__ __launch_bounds__(512) void proj_gemm256(
    const unsigned short* __restrict__ AO, const unsigned short* __restrict__ WpT,
    const float* __restrict__ proj_b, const float* __restrict__ x1,
    float* __restrict__ out)
{
    __shared__ unsigned short lds[65536];
    int bid = blockIdx.x;
    int wg  = (bid & 7) * 64 + (bid >> 3);     // XCD-bijective (512 = 8*64)
    int mb  = wg >> 1, nb = wg & 1;
    f32x4 acc[8][4];
#pragma unroll
    for (int mi = 0; mi < 8; mi++)
#pragma unroll
        for (int ni = 0; ni < 4; ni++) { f32x4 z = {0.f,0.f,0.f,0.f}; acc[mi][ni] = z; }
    gemm256(lds, AO + (size_t)mb * 256 * 512, WpT + (size_t)nb * 256 * 512, acc);

    int lane = threadIdx.x & 63, wv = threadIdx.x >> 6;
    int wr = wv >> 2, wc = wv & 3, lr = lane & 15, lk = lane >> 4;
    int base_m = mb * 256 + wr * 128;
#pragma unroll
    for (int ni = 0; ni < 4; ni++) {
        int col = nb * 256 + wc * 64 + ni * 16 + lr;
        float bias = proj_b[col];
#pragma unroll
        for (int mi = 0; mi < 8; mi++)
#pragma unroll
            for (int ii = 0; ii < 4; ii++) {
                int row = base_m + mi * 16 + lk * 4 + ii;
                out[(size_t)row * 512 + col] = acc[mi][ni][ii] + bias + x1[(size_t)row * 512 + col];
            }
    }
}

// ---------- 4a) bias table precompute in MFMA C-frag layout ----------
// biasC[h][fr][fc][lane][i] = rpb[REL(16fr+4lk+i, 16fc+lr)*16 + h]  (fp32, 256KB)
__global__ __launch_bounds__(256) void bias_pre(
    const float* __restrict__ rpb, float* __restrict__ biasC)
{
    int h = blockIdx.x;                    // 0..15
    int lane = threadIdx.x & 63;
    int fr = threadIdx.x >> 6;             // 0..3
    int lk = lane >> 4, lr = lane & 15;
#pragma unroll
    for (int fc = 0; fc < 4; fc++) {
        float4 v;
#pragma unroll
        for (int i = 0; i < 4; i++) {
            int n = 16 * fr + 4 * lk + i;
            int m = 16 * fc + lr;
            int idx = ((n >> 3) - (m >> 3) + 7) * 15 + (n & 7) - (m & 7) + 7;
            (&v.x)[i] = rpb[idx * 16 + h];
        }
        *(float4*)(biasC + (((h * 4 + fr) * 4 + fc) << 8) + (lane << 2)) = v;
    }
}

// ---------- 4) windowed cross-attention: one wave per (window, head) ----------
__global__ __launch_bounds__(256) void attn_kernel(
    const unsigned short* __restrict__ Qb, const unsigned short* __restrict__ KVb,
    const float* __restrict__ biasC, unsigned short* __restrict__ AO)
{
    __shared__ unsigned short sV[4][64 * 32];
    __shared__ unsigned short sP[4][64 * 64];
    int wv = threadIdx.x >> 6, lane = threadIdx.x & 63;
    int lr = lane & 15, lk = lane >> 4;
    int u = blockIdx.x * 4 + wv;           // 0..16383
    int win = u >> 4, h = u & 15;
    int b = win >> 6, wi = win & 63;
    int rowbase = b * 4096 + (wi >> 3) * 512 + (wi & 7) * 8;
    unsigned short* myV = sV[wv];
    unsigned short* myP = sP[wv];

#pragma unroll
    for (int i = 0; i < 4; i++) {
        int c = i * 64 + lane;             // 16B chunk id, 0..255
        int t = c >> 2, cc = c & 3;
        int grow = rowbase + (t >> 3) * 64 + (t & 7);
        *(short8*)(myV + t * 32 + cc * 8) =
            *(const short8*)(KVb + (size_t)grow * 1024 + 512 + h * 32 + cc * 8);
    }
    short8 qf[4], kf[4];
#pragma unroll
    for (int fr = 0; fr < 4; fr++) {
        int t = 16 * fr + lr;
        int grow = rowbase + (t >> 3) * 64 + (t & 7);
        qf[fr] = *(const short8*)(Qb  + (size_t)grow * 512  + h * 32 + lk * 8);
        kf[fr] = *(const short8*)(KVb + (size_t)grow * 1024 + h * 32 + lk * 8);
    }
    f32x4 s[4][4];
#pragma unroll
    for (int fr = 0; fr < 4; fr++)
#pragma unroll
        for (int fc = 0; fc < 4; fc++) { f32x4 z = {0.f,0.f,0.f,0.f}; s[fr][fc] = z; }
#pragma unroll
    for (int fr = 0; fr < 4; fr++)
#pragma unroll
        for (int fc = 0; fc < 4; fc++)
            s[fr][fc] = __builtin_amdgcn_mfma_f32_16x16x32_bf16(qf[fr], kf[fc], s[fr][fc], 0, 0, 0);

    const float* bch = biasC + (h << 12);   // h * 4096
    float rinv[4][4];
#pragma unroll
    for (int fr = 0; fr < 4; fr++) {
        f32x4 bb[4];
#pragma unroll
        for (int fc = 0; fc < 4; fc++)
            bb[fc] = *(const f32x4*)(bch + (((fr << 2) + fc) << 8) + (lane << 2));
#pragma unroll
        for (int i = 0; i < 4; i++) {
            int n = 16 * fr + 4 * lk + i;
#pragma unroll
            for (int fc = 0; fc < 4; fc++)
                s[fr][fc][i] += bb[fc][i];
            float v = fmaxf(fmaxf(s[fr][0][i], s[fr][1][i]), fmaxf(s[fr][2][i], s[fr][3][i]));
            v = fmaxf(v, __shfl_xor(v, 1)); v = fmaxf(v, __shfl_xor(v, 2));
            v = fmaxf(v, __shfl_xor(v, 4)); v = fmaxf(v, __shfl_xor(v, 8));
            float sum = 0.f;
#pragma unroll
            for (int fc = 0; fc < 4; fc++) {
                float e = __expf(s[fr][fc][i] - v);
                s[fr][fc][i] = e; sum += e;
            }
            sum += __shfl_xor(sum, 1); sum += __shfl_xor(sum, 2);
            sum += __shfl_xor(sum, 4); sum += __shfl_xor(sum, 8);
            rinv[fr][i] = 1.0f / sum;
#pragma unroll
            for (int fc = 0; fc < 4; fc++) {
                int m = 16 * fc + lr;
                int chunk = (m >> 3) ^ (n & 7);
                myP[n * 64 + chunk * 8 + (m & 7)] = f2bf(s[fr][fc][i]);
            }
        }
    }
    __syncthreads();

    f32x4 o[4][2];
#pragma unroll
    for (int fr = 0; fr < 4; fr++)
#pragma unroll
        for (int nj = 0; nj < 2; nj++) { f32x4 z = {0.f,0.f,0.f,0.f}; o[fr][nj] = z; }
#pragma unroll
    for (int mk = 0; mk < 2; mk++) {
        short8 pa[4];
#pragma unroll
        for (int fr = 0; fr < 4; fr++) {
            int n = 16 * fr + lr;
            int chunk = (4 * mk + lk) ^ (n & 7);
            pa[fr] = *(const short8*)(myP + n * 64 + chunk * 8);
        }
#pragma unroll
        for (int nj = 0; nj < 2; nj++) {
            short8 vb;
#pragma unroll
            for (int j = 0; j < 8; j++)
                vb[j] = (short)myV[(32 * mk + 8 * lk + j) * 32 + 16 * nj + lr];
#pragma unroll
            for (int fr = 0; fr < 4; fr++)
                o[fr][nj] = __builtin_amdgcn_mfma_f32_16x16x32_bf16(pa[fr], vb, o[fr][nj], 0, 0, 0);
        }
    }
#pragma unroll
    for (int fr = 0; fr < 4; fr++)
#pragma unroll
        for (int nj = 0; nj < 2; nj++)
#pragma unroll
            for (int i = 0; i < 4; i++) {
                int t = 16 * fr + 4 * lk + i;
                int grow = rowbase + (t >> 3) * 64 + (t & 7);
                AO[(size_t)grow * 512 + h * 32 + 16 * nj + lr] = f2bf(o[fr][nj][i] * rinv[fr][i]);
            }
}

// ---------- launch ----------
extern "C" void kernel_launch(void* const* d_in, const int* in_sizes, int n_in,
                              void* d_out, int out_size, void* d_ws, size_t ws_size,
                              hipStream_t stream)
{
    const float* x1     = (const float*)d_in[0];
    const float* x2     = (const float*)d_in[1];
    const float* n1w    = (const float*)d_in[2];
    const float* n1b    = (const float*)d_in[3];
    const float* n2w    = (const float*)d_in[4];
    const float* n2b    = (const float*)d_in[5];
    const float* qkv1_w = (const float*)d_in[6];
    const float* qkv1_b = (const float*)d_in[7];
    const float* qkv2_w = (const float*)d_in[8];
    const float* qkv2_b = (const float*)d_in[9];
    const float* rpb    = (const float*)d_in[10];
    const float* proj_w = (const float*)d_in[11];
    const float* proj_b = (const float*)d_in[12];
    float* out = (float*)d_out;

    char* ws = (char*)d_ws;
    const size_t SZ = 67108864;   // 65536*512*2 bytes
    unsigned short* XN1  = (unsigned short*)(ws);
    unsigned short* XN2  = (unsigned short*)(ws + SZ);
    unsigned short* Qb   = (unsigned short*)(ws + 2 * SZ);
    unsigned short* KVb  = (unsigned short*)(ws + 3 * SZ);       // 128MB (K then V)
    unsigned short* WqT  = (unsigned short*)(ws + 5 * SZ);
    unsigned short* WkvT = WqT + 512 * 512;
    unsigned short* WpT  = WkvT + 1024 * 512;
    unsigned short* AO   = XN2;   // XN2 dead after qkv gemm; reuse for attention output
    float* biasC = (float*)ws;    // aliases XN1 (dead after qkv); 256 KB, written post-qkv

    hipLaunchKernelGGL(ln_kernel,     dim3(32768), dim3(256), 0, stream,
                       x1, x2, n1w, n1b, n2w, n2b, XN1, XN2);
    hipLaunchKernelGGL(wconv_kernel,  dim3(1024),  dim3(256), 0, stream,
                       qkv1_w, qkv2_w, proj_w, WqT, WkvT, WpT);
    hipLaunchKernelGGL(qkv_gemm256,   dim3(1536),  dim3(512), 0, stream,
                       XN1, XN2, WqT, WkvT, qkv1_b, qkv2_b, Qb, KVb);
    hipLaunchKernelGGL(bias_pre,      dim3(16),    dim3(256), 0, stream,
                       rpb, biasC);
    hipLaunchKernelGGL(attn_kernel,   dim3(4096),  dim3(256), 0, stream,
                       Qb, KVb, biasC, AO);
    hipLaunchKernelGGL(proj_gemm256,  dim3(512),   dim3(512), 0, stream,
                       AO, WpT, proj_b, x1, out);
}